// Round 7
// baseline (1027.834 us; speedup 1.0000x reference)
//
#include <hip/hip_runtime.h>
#include <hip/hip_bf16.h>

// ---------- helpers ----------
__device__ inline unsigned fkey(float x) {
    unsigned u = __float_as_uint(x);
    return (u & 0x80000000u) ? ~u : (u | 0x80000000u);
}
__device__ inline float funkey(unsigned k) {
    unsigned u = (k & 0x80000000u) ? (k & 0x7FFFFFFFu) : ~k;
    return __uint_as_float(u);
}
__device__ inline float lrelu(float x) { return x > 0.f ? x : 0.2f * x; }

// ---------- fold attention vectors through W: Walr[k][2H] ----------
__global__ void fold_attn(const float* __restrict__ W, const float* __restrict__ al,
                          const float* __restrict__ ar, float* __restrict__ Walr,
                          int H, int D) {
    int k = blockIdx.x;
    int lane = threadIdx.x;
    int C = H * D;
    for (int h = 0; h < H; ++h) {
        float sl = 0.f, sr = 0.f;
        for (int d = lane; d < D; d += 64) {
            float w = W[(size_t)k * C + h * D + d];
            sl += w * al[h * D + d];
            sr += w * ar[h * D + d];
        }
        for (int off = 32; off; off >>= 1) {
            sl += __shfl_down(sl, off);
            sr += __shfl_down(sr, off);
        }
        if (lane == 0) {
            Walr[k * 2 * H + h] = sl;
            Walr[k * 2 * H + H + h] = sr;
        }
    }
}

// ---------- el/er from 64-dim input: one wave per node ----------
__global__ void attn_from_x(const float* __restrict__ in, const float* __restrict__ Walr,
                            float* __restrict__ el, float* __restrict__ er, int N, int H) {
    int lane = threadIdx.x & 63;
    int wib = threadIdx.x >> 6;
    int wpb = blockDim.x >> 6;
    int wstride = gridDim.x * wpb;
    int H2 = 2 * H;
    for (int n = blockIdx.x * wpb + wib; n < N; n += wstride) {
        float x = in[(size_t)n * 64 + lane];
        const float* wrow = Walr + lane * H2;
        for (int h = 0; h < H2; ++h) {
            float s = x * wrow[h];
            for (int off = 32; off; off >>= 1) s += __shfl_down(s, off);
            if (lane == 0) {
                if (h < H) el[(size_t)n * H + h] = s;
                else       er[(size_t)n * H + h - H] = s;
            }
        }
    }
}

// ---------- CSR build ----------
__global__ void count_deg(const int* __restrict__ dst, int* __restrict__ deg, int E) {
    int stride = gridDim.x * blockDim.x;
    for (int i = blockIdx.x * blockDim.x + threadIdx.x; i < E; i += stride)
        atomicAdd(&deg[dst[i]], 1);
}

__global__ void build_rowptr(const int* __restrict__ deg, int* __restrict__ rowptr, int N) {
    __shared__ int ssum[1024];
    int t = threadIdx.x;
    int nt = blockDim.x;
    int chunk = (N + nt - 1) / nt;
    int beg = t * chunk;
    int end = beg + chunk; if (end > N) end = N; if (beg > N) beg = N;
    int s = 0;
    for (int i = beg; i < end; ++i) s += deg[i];
    ssum[t] = s;
    __syncthreads();
    for (int off = 1; off < nt; off <<= 1) {
        int v = (t >= off) ? ssum[t - off] : 0;
        __syncthreads();
        ssum[t] += v;
        __syncthreads();
    }
    int run = (t == 0) ? 0 : ssum[t - 1];
    for (int i = beg; i < end; ++i) { rowptr[i] = run; run += deg[i]; }
    if (t == nt - 1) rowptr[N] = run;
}

__global__ void fill_adj(const int* __restrict__ src, const int* __restrict__ dst,
                         int* __restrict__ cursor, int* __restrict__ adj,
                         int* __restrict__ dslot, int E) {
    int stride = gridDim.x * blockDim.x;
    for (int i = blockIdx.x * blockDim.x + threadIdx.x; i < E; i += stride) {
        int d = dst[i];
        int pos = atomicAdd(&cursor[d], 1);
        adj[pos] = src[i];
        dslot[pos] = d;
    }
}

// ---------- per-slot raw attention logits (edge-parallel, coalesced) ----------
template <int H>
__global__ void edge_e(const int* __restrict__ adj, const int* __restrict__ dslot,
                       const float* __restrict__ el, const float* __restrict__ er,
                       float* __restrict__ e, int E) {
    int stride = gridDim.x * blockDim.x;
    for (int i = blockIdx.x * blockDim.x + threadIdx.x; i < E; i += stride) {
        int s = adj[i], d = dslot[i];
        const float* els = el + (size_t)s * H;
        const float* erd = er + (size_t)d * H;
#pragma unroll
        for (int h = 0; h < H; ++h)
            e[(size_t)i * H + h] = lrelu(els[h] + erd[h]);
    }
}

// ---------- per-node softmax normalize: thread per node, contiguous e range ----------
template <int H>
__global__ void node_norm(const int* __restrict__ rowptr, const float* __restrict__ e,
                          float* __restrict__ alpha, int N) {
    int stride = gridDim.x * blockDim.x;
    for (int n = blockIdx.x * blockDim.x + threadIdx.x; n < N; n += stride) {
        int rbeg = rowptr[n], rend = rowptr[n + 1];
        if (rbeg == rend) continue;
        float m[H], den[H];
#pragma unroll
        for (int h = 0; h < H; ++h) { m[h] = -INFINITY; den[h] = 0.f; }
        for (int j = rbeg; j < rend; ++j) {
#pragma unroll
            for (int h = 0; h < H; ++h) {
                float ev = e[(size_t)j * H + h];
                float newm = fmaxf(m[h], ev);
                den[h] = den[h] * __expf(m[h] - newm) + __expf(ev - newm);
                m[h] = newm;
            }
        }
        float inv[H];
#pragma unroll
        for (int h = 0; h < H; ++h) inv[h] = 1.f / fmaxf(den[h], 1e-9f);
        for (int j = rbeg; j < rend; ++j) {
#pragma unroll
            for (int h = 0; h < H; ++h)
                alpha[(size_t)j * H + h] = __expf(e[(size_t)j * H + h] - m[h]) * inv[h];
        }
    }
}

// ---------- gather RAW input rows weighted by alpha: z[n][h*64+lane] ----------
// Aggregate-then-project: z = sum_j alpha_h(j) * x[src_j] (64-dim rows, L2-resident).
template <int H>
__global__ __launch_bounds__(256, 8) void gather_z(
        const int* __restrict__ rowptr, const int* __restrict__ adj,
        const float* __restrict__ alpha, const float* __restrict__ x,
        float* __restrict__ z, int N) {
    int lane = threadIdx.x & 63;
    int w = threadIdx.x >> 6;
    int wpb = blockDim.x >> 6;
    int wstride = gridDim.x * wpb;
    for (int n = blockIdx.x * wpb + w; n < N; n += wstride) {
        int rbeg = __builtin_amdgcn_readfirstlane(rowptr[n]);
        int rend = __builtin_amdgcn_readfirstlane(rowptr[n + 1]);
        float acc[H];
#pragma unroll
        for (int h = 0; h < H; ++h) acc[h] = 0.f;
        for (int j = rbeg; j < rend; ++j) {
            int s = __builtin_amdgcn_readfirstlane(adj[j]);
            float xv = x[(size_t)s * 64 + lane];
            const float* al = alpha + (size_t)j * H;
#pragma unroll
            for (int h = 0; h < H; ++h) acc[h] += al[h] * xv;
        }
#pragma unroll
        for (int h = 0; h < H; ++h)
            z[(size_t)n * (H * 64) + h * 64 + lane] = acc[h];
    }
}

// ---------- per-head projection + relu + head-sum ----------
// h1[n,d] = sum_h relu( z[n][h*64+:] @ W[:, h*64+d] + bias[h*64+d] ), d in [0,64)
template <int H>
__global__ __launch_bounds__(256, 4) void gemm_heads(const float* __restrict__ z,
                                                     const float* __restrict__ W,
                                                     const float* __restrict__ bias,
                                                     float* __restrict__ out, int N) {
    const int SA = H * 64;  // row stride of z and W
    __shared__ __align__(16) float As[64][68];
    __shared__ __align__(16) float Bs[64][64];
    int row0 = blockIdx.x * 64;
    int t = threadIdx.x;
    int c0 = (t & 15) * 4;
    int r0 = (t >> 4) * 4;

    float4 o[4];
#pragma unroll
    for (int i = 0; i < 4; ++i) o[i] = make_float4(0.f, 0.f, 0.f, 0.f);

    for (int h = 0; h < H; ++h) {
        __syncthreads();
        // stage z_h tile (rows row0..row0+63, cols h*64..h*64+63)
#pragma unroll
        for (int p = 0; p < 4; ++p) {
            int idx = t + p * 256;
            int r = idx >> 4, k0 = (idx & 15) << 2;
            float4 v = make_float4(0.f, 0.f, 0.f, 0.f);
            if (row0 + r < N)
                v = *reinterpret_cast<const float4*>(&z[(size_t)(row0 + r) * SA + h * 64 + k0]);
            *reinterpret_cast<float4*>(&As[r][k0]) = v;
        }
        // stage W_h tile
#pragma unroll
        for (int p = 0; p < 4; ++p) {
            int idx = t + p * 256;
            int k = idx >> 4, cc = (idx & 15) << 2;
            float4 v = *reinterpret_cast<const float4*>(&W[(size_t)k * SA + h * 64 + cc]);
            *reinterpret_cast<float4*>(&Bs[k][cc]) = v;
        }
        __syncthreads();

        float4 acc[4];
#pragma unroll
        for (int i = 0; i < 4; ++i) acc[i] = make_float4(0.f, 0.f, 0.f, 0.f);
#pragma unroll 2
        for (int k0 = 0; k0 < 64; k0 += 4) {
            float4 a[4], b[4];
#pragma unroll
            for (int i = 0; i < 4; ++i) a[i] = *reinterpret_cast<const float4*>(&As[r0 + i][k0]);
#pragma unroll
            for (int j = 0; j < 4; ++j) b[j] = *reinterpret_cast<const float4*>(&Bs[k0 + j][c0]);
#pragma unroll
            for (int i = 0; i < 4; ++i) {
                acc[i].x += a[i].x * b[0].x + a[i].y * b[1].x + a[i].z * b[2].x + a[i].w * b[3].x;
                acc[i].y += a[i].x * b[0].y + a[i].y * b[1].y + a[i].z * b[2].y + a[i].w * b[3].y;
                acc[i].z += a[i].x * b[0].z + a[i].y * b[1].z + a[i].z * b[2].z + a[i].w * b[3].z;
                acc[i].w += a[i].x * b[0].w + a[i].y * b[1].w + a[i].z * b[2].w + a[i].w * b[3].w;
            }
        }
        float4 bv = *reinterpret_cast<const float4*>(&bias[h * 64 + c0]);
#pragma unroll
        for (int i = 0; i < 4; ++i) {
            float vx = acc[i].x + bv.x, vy = acc[i].y + bv.y;
            float vz = acc[i].z + bv.z, vw = acc[i].w + bv.w;
            o[i].x += vx > 0.f ? vx : 0.f;
            o[i].y += vy > 0.f ? vy : 0.f;
            o[i].z += vz > 0.f ? vz : 0.f;
            o[i].w += vw > 0.f ? vw : 0.f;
        }
    }

#pragma unroll
    for (int i = 0; i < 4; ++i) {
        int row = row0 + r0 + i;
        if (row < N)
            *reinterpret_cast<float4*>(&out[(size_t)row * 64 + c0]) = o[i];
    }
}

// ---------- layer-2 final GEMM: rst2 = z2 @ W2, +bias, relu, graph atomicMax ----------
// A = z2 [N x 64] contiguous, B = W2 [64 x 128], grid.y covers 128 cols.
__global__ __launch_bounds__(256, 4) void gemm_final(const float* __restrict__ A,
                                                     const float* __restrict__ B,
                                                     const float* __restrict__ bias,
                                                     const int* __restrict__ gid,
                                                     unsigned* __restrict__ gk, int N) {
    const int C = 128;
    __shared__ __align__(16) float As[64][68];
    __shared__ __align__(16) float Bs[64][64];
    int row0 = blockIdx.x * 64;
    int col0 = blockIdx.y * 64;
    int t = threadIdx.x;

    const float* Abase = A + (size_t)row0 * 64;
    int maxElems = (N - row0) * 64;
#pragma unroll
    for (int p = 0; p < 4; ++p) {
        int idx = t + p * 256;
        int r = idx >> 4, k0 = (idx & 15) << 2;
        float4 v = make_float4(0.f, 0.f, 0.f, 0.f);
        if (idx * 4 < maxElems) v = *reinterpret_cast<const float4*>(Abase + (size_t)idx * 4);
        *reinterpret_cast<float4*>(&As[r][k0]) = v;
    }
#pragma unroll
    for (int p = 0; p < 4; ++p) {
        int idx = t + p * 256;
        int k = idx >> 4, cc = (idx & 15) << 2;
        float4 v = *reinterpret_cast<const float4*>(&B[(size_t)k * C + col0 + cc]);
        *reinterpret_cast<float4*>(&Bs[k][cc]) = v;
    }
    __syncthreads();

    int c0 = (t & 15) * 4;
    int r0 = (t >> 4) * 4;
    float4 acc[4];
#pragma unroll
    for (int i = 0; i < 4; ++i) acc[i] = make_float4(0.f, 0.f, 0.f, 0.f);

#pragma unroll 2
    for (int k0 = 0; k0 < 64; k0 += 4) {
        float4 a[4], b[4];
#pragma unroll
        for (int i = 0; i < 4; ++i) a[i] = *reinterpret_cast<const float4*>(&As[r0 + i][k0]);
#pragma unroll
        for (int j = 0; j < 4; ++j) b[j] = *reinterpret_cast<const float4*>(&Bs[k0 + j][c0]);
#pragma unroll
        for (int i = 0; i < 4; ++i) {
            acc[i].x += a[i].x * b[0].x + a[i].y * b[1].x + a[i].z * b[2].x + a[i].w * b[3].x;
            acc[i].y += a[i].x * b[0].y + a[i].y * b[1].y + a[i].z * b[2].y + a[i].w * b[3].y;
            acc[i].z += a[i].x * b[0].z + a[i].y * b[1].z + a[i].z * b[2].z + a[i].w * b[3].z;
            acc[i].w += a[i].x * b[0].w + a[i].y * b[1].w + a[i].z * b[2].w + a[i].w * b[3].w;
        }
    }

    float4 bv = *reinterpret_cast<const float4*>(&bias[col0 + c0]);
#pragma unroll
    for (int i = 0; i < 4; ++i) {
        int row = row0 + r0 + i;
        if (row < N) {
            int g = gid[row];
            unsigned* gkg = gk + (size_t)g * C + col0 + c0;
            float vx = acc[i].x + bv.x, vy = acc[i].y + bv.y;
            float vz = acc[i].z + bv.z, vw = acc[i].w + bv.w;
            atomicMax(&gkg[0], fkey(vx > 0.f ? vx : 0.f));
            atomicMax(&gkg[1], fkey(vy > 0.f ? vy : 0.f));
            atomicMax(&gkg[2], fkey(vz > 0.f ? vz : 0.f));
            atomicMax(&gkg[3], fkey(vw > 0.f ? vw : 0.f));
        }
    }
}

// ---------- head MLP ----------
__global__ void mlp_head(const unsigned* __restrict__ gkl, const unsigned* __restrict__ gkr,
                         const float* __restrict__ W1, const float* __restrict__ b1,
                         const float* __restrict__ W2, const float* __restrict__ b2,
                         float* __restrict__ out) {
    __shared__ float hcat[32][256];
    __shared__ float h[32][128];
    int t = threadIdx.x;  // 256 threads
    for (int i = t; i < 32 * 128; i += 256) {
        int r = i / 128, c = i % 128;
        unsigned kl = gkl[i];
        unsigned kr = gkr[i];
        hcat[r][c] = (kl == 0u) ? 0.f : funkey(kl);
        hcat[r][128 + c] = (kr == 0u) ? 0.f : funkey(kr);
    }
    __syncthreads();
    for (int i = t; i < 32 * 128; i += 256) {
        int r = i / 128, c = i % 128;
        float acc = b1[c];
        for (int k = 0; k < 256; ++k) acc += hcat[r][k] * W1[k * 128 + c];
        h[r][c] = acc > 0.f ? acc : 0.f;
    }
    __syncthreads();
    if (t < 32) {
        float acc = b2[0];
        for (int k = 0; k < 128; ++k) acc += h[t][k] * W2[k];
        out[t] = acc > 0.f ? acc : 0.f;
    }
}

// ---------- launch ----------
static inline unsigned nblk_elem(long long total) {
    long long b = (total + 255) / 256;
    if (b > 65535) b = 65535;
    if (b < 1) b = 1;
    return (unsigned)b;
}
static inline unsigned nblk_gather(long long nodes) {
    long long b = (nodes + 3) / 4;
    if (b > 65535) b = 65535;
    if (b < 1) b = 1;
    return (unsigned)b;
}

extern "C" void kernel_launch(void* const* d_in, const int* in_sizes, int n_in,
                              void* d_out, int out_size, void* d_ws, size_t ws_size,
                              hipStream_t stream) {
    const float* lig_x = (const float*)d_in[0];
    const int* lig_src = (const int*)d_in[1];
    const int* lig_dst = (const int*)d_in[2];
    const int* lig_gid = (const int*)d_in[3];
    const float* rec_x = (const float*)d_in[4];
    const int* rec_src = (const int*)d_in[5];
    const int* rec_dst = (const int*)d_in[6];
    const int* rec_gid = (const int*)d_in[7];
    const float* W1l = (const float*)d_in[8];
    const float* al1l = (const float*)d_in[9];
    const float* ar1l = (const float*)d_in[10];
    const float* b1l = (const float*)d_in[11];
    const float* W2l = (const float*)d_in[12];
    const float* al2l = (const float*)d_in[13];
    const float* ar2l = (const float*)d_in[14];
    const float* b2l = (const float*)d_in[15];
    const float* W1r = (const float*)d_in[16];
    const float* al1r = (const float*)d_in[17];
    const float* ar1r = (const float*)d_in[18];
    const float* b1r = (const float*)d_in[19];
    const float* W2r = (const float*)d_in[20];
    const float* al2r = (const float*)d_in[21];
    const float* ar2r = (const float*)d_in[22];
    const float* b2r = (const float*)d_in[23];
    const float* Wlin1 = (const float*)d_in[24];
    const float* blin1 = (const float*)d_in[25];
    const float* Wlin2 = (const float*)d_in[26];
    const float* blin2 = (const float*)d_in[27];

    int Nl = in_sizes[0] / 64, El = in_sizes[1];
    int Nr = in_sizes[4] / 64, Er = in_sizes[5];
    long long Nmax = Nl > Nr ? Nl : Nr;
    long long Emax = El > Er ? El : Er;

    // workspace layout
    char* ws = (char*)d_ws;
    float* z = (float*)ws;           ws += Nmax * 640 * 4;  // layer1 z; layer2 z2 aliases
    float* h1 = (float*)ws;          ws += Nmax * 64 * 4;
    float* elb = (float*)ws;         ws += Nmax * 10 * 4;
    float* erb = (float*)ws;         ws += Nmax * 10 * 4;
    int* deg = (int*)ws;             ws += Nmax * 4;
    int* cursor = (int*)ws;          ws += Nmax * 4;
    int* rowptr = (int*)ws;          ws += (Nmax + 1) * 4;
    int* adj = (int*)ws;             ws += Emax * 4;
    int* dslot = (int*)ws;           ws += Emax * 4;
    float* ebuf = (float*)ws;        ws += Emax * 10 * 4;
    float* alpha = (float*)ws;       ws += Emax * 10 * 4;
    unsigned* gkl = (unsigned*)ws;   ws += 32 * 128 * 4;
    unsigned* gkr = (unsigned*)ws;   ws += 32 * 128 * 4;
    float* Walr = (float*)ws;        ws += 64 * 32 * 4;
    float* z2 = z;  // [N,64], reused after gemm_heads consumed z

    hipMemsetAsync(gkl, 0, 32 * 128 * 4, stream);
    hipMemsetAsync(gkr, 0, 32 * 128 * 4, stream);

    auto run_branch = [&](const float* x, const int* src, const int* dst, const int* gid,
                          const float* W1, const float* al1, const float* ar1, const float* b1,
                          const float* W2, const float* al2, const float* ar2, const float* b2,
                          unsigned* gk, int N, int E) {
        // CSR (shared by both layers)
        hipMemsetAsync(deg, 0, (size_t)N * 4, stream);
        count_deg<<<nblk_elem(E), 256, 0, stream>>>(dst, deg, E);
        build_rowptr<<<1, 1024, 0, stream>>>(deg, rowptr, N);
        hipMemcpyAsync(cursor, rowptr, (size_t)N * 4, hipMemcpyDeviceToDevice, stream);
        fill_adj<<<nblk_elem(E), 256, 0, stream>>>(src, dst, cursor, adj, dslot, E);

        // ---- layer 1: H=10, aggregate x then project ----
        fold_attn<<<64, 64, 0, stream>>>(W1, al1, ar1, Walr, 10, 64);
        attn_from_x<<<nblk_gather(N), 256, 0, stream>>>(x, Walr, elb, erb, N, 10);
        edge_e<10><<<nblk_elem(E), 256, 0, stream>>>(adj, dslot, elb, erb, ebuf, E);
        node_norm<10><<<nblk_elem(N), 256, 0, stream>>>(rowptr, ebuf, alpha, N);
        gather_z<10><<<nblk_gather(N), 256, 0, stream>>>(rowptr, adj, alpha, x, z, N);
        gemm_heads<10><<<(N + 63) / 64, 256, 0, stream>>>(z, W1, b1, h1, N);

        // ---- layer 2: H=1, aggregate h1 then project (fused graph-max) ----
        fold_attn<<<64, 64, 0, stream>>>(W2, al2, ar2, Walr, 1, 128);
        attn_from_x<<<nblk_gather(N), 256, 0, stream>>>(h1, Walr, elb, erb, N, 1);
        edge_e<1><<<nblk_elem(E), 256, 0, stream>>>(adj, dslot, elb, erb, ebuf, E);
        node_norm<1><<<nblk_elem(N), 256, 0, stream>>>(rowptr, ebuf, alpha, N);
        gather_z<1><<<nblk_gather(N), 256, 0, stream>>>(rowptr, adj, alpha, h1, z2, N);
        gemm_final<<<dim3((N + 63) / 64, 2), 256, 0, stream>>>(z2, W2, b2, gid, gk, N);
    };

    run_branch(lig_x, lig_src, lig_dst, lig_gid, W1l, al1l, ar1l, b1l, W2l, al2l, ar2l, b2l,
               gkl, Nl, El);
    run_branch(rec_x, rec_src, rec_dst, rec_gid, W1r, al1r, ar1r, b1r, W2r, al2r, ar2r, b2r,
               gkr, Nr, Er);

    mlp_head<<<1, 256, 0, stream>>>(gkl, gkr, Wlin1, blin1, Wlin2, blin2, (float*)d_out);
}

// Round 8
// 722.534 us; speedup vs baseline: 1.4225x; 1.4225x over previous
//
#include <hip/hip_runtime.h>
#include <hip/hip_bf16.h>

__device__ inline float lrelu(float x) { return x > 0.f ? x : 0.2f * x; }

// ---------- fold attention vectors through W: Walr[k][2H] ----------
__global__ void fold_attn(const float* __restrict__ W, const float* __restrict__ al,
                          const float* __restrict__ ar, float* __restrict__ Walr,
                          int H, int D) {
    int k = blockIdx.x;
    int lane = threadIdx.x;
    int C = H * D;
    for (int h = 0; h < H; ++h) {
        float sl = 0.f, sr = 0.f;
        for (int d = lane; d < D; d += 64) {
            float w = W[(size_t)k * C + h * D + d];
            sl += w * al[h * D + d];
            sr += w * ar[h * D + d];
        }
        for (int off = 32; off; off >>= 1) {
            sl += __shfl_down(sl, off);
            sr += __shfl_down(sr, off);
        }
        if (lane == 0) {
            Walr[k * 2 * H + h] = sl;
            Walr[k * 2 * H + H + h] = sr;
        }
    }
}

// ---------- el/er from 64-dim input: one wave per node ----------
__global__ void attn_from_x(const float* __restrict__ in, const float* __restrict__ Walr,
                            float* __restrict__ el, float* __restrict__ er, int N, int H) {
    int lane = threadIdx.x & 63;
    int wib = threadIdx.x >> 6;
    int wpb = blockDim.x >> 6;
    int wstride = gridDim.x * wpb;
    int H2 = 2 * H;
    for (int n = blockIdx.x * wpb + wib; n < N; n += wstride) {
        float x = in[(size_t)n * 64 + lane];
        const float* wrow = Walr + lane * H2;
        for (int h = 0; h < H2; ++h) {
            float s = x * wrow[h];
            for (int off = 32; off; off >>= 1) s += __shfl_down(s, off);
            if (lane == 0) {
                if (h < H) el[(size_t)n * H + h] = s;
                else       er[(size_t)n * H + h - H] = s;
            }
        }
    }
}

// ---------- CSR build ----------
__global__ void count_deg(const int* __restrict__ dst, int* __restrict__ deg, int E) {
    int stride = gridDim.x * blockDim.x;
    for (int i = blockIdx.x * blockDim.x + threadIdx.x; i < E; i += stride)
        atomicAdd(&deg[dst[i]], 1);
}

__global__ void build_rowptr(const int* __restrict__ deg, int* __restrict__ rowptr, int N) {
    __shared__ int ssum[1024];
    int t = threadIdx.x;
    int nt = blockDim.x;
    int chunk = (N + nt - 1) / nt;
    int beg = t * chunk;
    int end = beg + chunk; if (end > N) end = N; if (beg > N) beg = N;
    int s = 0;
    for (int i = beg; i < end; ++i) s += deg[i];
    ssum[t] = s;
    __syncthreads();
    for (int off = 1; off < nt; off <<= 1) {
        int v = (t >= off) ? ssum[t - off] : 0;
        __syncthreads();
        ssum[t] += v;
        __syncthreads();
    }
    int run = (t == 0) ? 0 : ssum[t - 1];
    for (int i = beg; i < end; ++i) { rowptr[i] = run; run += deg[i]; }
    if (t == nt - 1) rowptr[N] = run;
}

__global__ void fill_adj(const int* __restrict__ src, const int* __restrict__ dst,
                         int* __restrict__ cursor, int* __restrict__ adj,
                         int* __restrict__ dslot, int E) {
    int stride = gridDim.x * blockDim.x;
    for (int i = blockIdx.x * blockDim.x + threadIdx.x; i < E; i += stride) {
        int d = dst[i];
        int pos = atomicAdd(&cursor[d], 1);
        adj[pos] = src[i];
        dslot[pos] = d;
    }
}

// ---------- graph segment boundaries from SORTED gid: gstart[g] = first n with gid[n] >= g ----------
__global__ void gstart_build(const int* __restrict__ gid, int* __restrict__ gstart,
                             int N, int NG) {
    int stride = gridDim.x * blockDim.x;
    for (int n = blockIdx.x * blockDim.x + threadIdx.x; n < N; n += stride) {
        int gcur = gid[n];
        int gprev = (n == 0) ? -1 : gid[n - 1];
        for (int g = gprev + 1; g <= gcur; ++g) gstart[g] = n;
        if (n == N - 1)
            for (int g = gcur + 1; g <= NG; ++g) gstart[g] = N;
    }
}

// ---------- per-slot raw attention logits (edge-parallel, coalesced) ----------
template <int H>
__global__ void edge_e(const int* __restrict__ adj, const int* __restrict__ dslot,
                       const float* __restrict__ el, const float* __restrict__ er,
                       float* __restrict__ e, int E) {
    int stride = gridDim.x * blockDim.x;
    for (int i = blockIdx.x * blockDim.x + threadIdx.x; i < E; i += stride) {
        int s = adj[i], d = dslot[i];
        const float* els = el + (size_t)s * H;
        const float* erd = er + (size_t)d * H;
#pragma unroll
        for (int h = 0; h < H; ++h)
            e[(size_t)i * H + h] = lrelu(els[h] + erd[h]);
    }
}

// ---------- per-node softmax normalize: thread per node, contiguous e range ----------
template <int H>
__global__ void node_norm(const int* __restrict__ rowptr, const float* __restrict__ e,
                          float* __restrict__ alpha, int N) {
    int stride = gridDim.x * blockDim.x;
    for (int n = blockIdx.x * blockDim.x + threadIdx.x; n < N; n += stride) {
        int rbeg = rowptr[n], rend = rowptr[n + 1];
        if (rbeg == rend) continue;
        float m[H], den[H];
#pragma unroll
        for (int h = 0; h < H; ++h) { m[h] = -INFINITY; den[h] = 0.f; }
        for (int j = rbeg; j < rend; ++j) {
#pragma unroll
            for (int h = 0; h < H; ++h) {
                float ev = e[(size_t)j * H + h];
                float newm = fmaxf(m[h], ev);
                den[h] = den[h] * __expf(m[h] - newm) + __expf(ev - newm);
                m[h] = newm;
            }
        }
        float inv[H];
#pragma unroll
        for (int h = 0; h < H; ++h) inv[h] = 1.f / fmaxf(den[h], 1e-9f);
        for (int j = rbeg; j < rend; ++j) {
#pragma unroll
            for (int h = 0; h < H; ++h)
                alpha[(size_t)j * H + h] = __expf(e[(size_t)j * H + h] - m[h]) * inv[h];
        }
    }
}

// ---------- gather RAW input rows weighted by alpha: z[n][h*64+lane] ----------
template <int H>
__global__ __launch_bounds__(256, 8) void gather_z(
        const int* __restrict__ rowptr, const int* __restrict__ adj,
        const float* __restrict__ alpha, const float* __restrict__ x,
        float* __restrict__ z, int N) {
    int lane = threadIdx.x & 63;
    int w = threadIdx.x >> 6;
    int wpb = blockDim.x >> 6;
    int wstride = gridDim.x * wpb;
    for (int n = blockIdx.x * wpb + w; n < N; n += wstride) {
        int rbeg = __builtin_amdgcn_readfirstlane(rowptr[n]);
        int rend = __builtin_amdgcn_readfirstlane(rowptr[n + 1]);
        float acc[H];
#pragma unroll
        for (int h = 0; h < H; ++h) acc[h] = 0.f;
        for (int j = rbeg; j < rend; ++j) {
            int s = __builtin_amdgcn_readfirstlane(adj[j]);
            float xv = x[(size_t)s * 64 + lane];
            const float* al = alpha + (size_t)j * H;
#pragma unroll
            for (int h = 0; h < H; ++h) acc[h] += al[h] * xv;
        }
#pragma unroll
        for (int h = 0; h < H; ++h)
            z[(size_t)n * (H * 64) + h * 64 + lane] = acc[h];
    }
}

// ---------- per-head projection + relu + head-sum ----------
template <int H>
__global__ __launch_bounds__(256, 4) void gemm_heads(const float* __restrict__ z,
                                                     const float* __restrict__ W,
                                                     const float* __restrict__ bias,
                                                     float* __restrict__ out, int N) {
    const int SA = H * 64;
    __shared__ __align__(16) float As[64][68];
    __shared__ __align__(16) float Bs[64][64];
    int row0 = blockIdx.x * 64;
    int t = threadIdx.x;
    int c0 = (t & 15) * 4;
    int r0 = (t >> 4) * 4;

    float4 o[4];
#pragma unroll
    for (int i = 0; i < 4; ++i) o[i] = make_float4(0.f, 0.f, 0.f, 0.f);

    for (int h = 0; h < H; ++h) {
        __syncthreads();
#pragma unroll
        for (int p = 0; p < 4; ++p) {
            int idx = t + p * 256;
            int r = idx >> 4, k0 = (idx & 15) << 2;
            float4 v = make_float4(0.f, 0.f, 0.f, 0.f);
            if (row0 + r < N)
                v = *reinterpret_cast<const float4*>(&z[(size_t)(row0 + r) * SA + h * 64 + k0]);
            *reinterpret_cast<float4*>(&As[r][k0]) = v;
        }
#pragma unroll
        for (int p = 0; p < 4; ++p) {
            int idx = t + p * 256;
            int k = idx >> 4, cc = (idx & 15) << 2;
            float4 v = *reinterpret_cast<const float4*>(&W[(size_t)k * SA + h * 64 + cc]);
            *reinterpret_cast<float4*>(&Bs[k][cc]) = v;
        }
        __syncthreads();

        float4 acc[4];
#pragma unroll
        for (int i = 0; i < 4; ++i) acc[i] = make_float4(0.f, 0.f, 0.f, 0.f);
#pragma unroll 2
        for (int k0 = 0; k0 < 64; k0 += 4) {
            float4 a[4], b[4];
#pragma unroll
            for (int i = 0; i < 4; ++i) a[i] = *reinterpret_cast<const float4*>(&As[r0 + i][k0]);
#pragma unroll
            for (int j = 0; j < 4; ++j) b[j] = *reinterpret_cast<const float4*>(&Bs[k0 + j][c0]);
#pragma unroll
            for (int i = 0; i < 4; ++i) {
                acc[i].x += a[i].x * b[0].x + a[i].y * b[1].x + a[i].z * b[2].x + a[i].w * b[3].x;
                acc[i].y += a[i].x * b[0].y + a[i].y * b[1].y + a[i].z * b[2].y + a[i].w * b[3].y;
                acc[i].z += a[i].x * b[0].z + a[i].y * b[1].z + a[i].z * b[2].z + a[i].w * b[3].z;
                acc[i].w += a[i].x * b[0].w + a[i].y * b[1].w + a[i].z * b[2].w + a[i].w * b[3].w;
            }
        }
        float4 bv = *reinterpret_cast<const float4*>(&bias[h * 64 + c0]);
#pragma unroll
        for (int i = 0; i < 4; ++i) {
            float vx = acc[i].x + bv.x, vy = acc[i].y + bv.y;
            float vz = acc[i].z + bv.z, vw = acc[i].w + bv.w;
            o[i].x += vx > 0.f ? vx : 0.f;
            o[i].y += vy > 0.f ? vy : 0.f;
            o[i].z += vz > 0.f ? vz : 0.f;
            o[i].w += vw > 0.f ? vw : 0.f;
        }
    }

#pragma unroll
    for (int i = 0; i < 4; ++i) {
        int row = row0 + r0 + i;
        if (row < N)
            *reinterpret_cast<float4*>(&out[(size_t)row * 64 + c0]) = o[i];
    }
}

// ---------- layer-2 final GEMM: rst2 = relu(z2 @ W2 + bias), plain stores ----------
__global__ __launch_bounds__(256, 4) void gemm_relu(const float* __restrict__ A,
                                                    const float* __restrict__ B,
                                                    const float* __restrict__ bias,
                                                    float* __restrict__ out, int N) {
    const int C = 128;
    __shared__ __align__(16) float As[64][68];
    __shared__ __align__(16) float Bs[64][64];
    int row0 = blockIdx.x * 64;
    int col0 = blockIdx.y * 64;
    int t = threadIdx.x;

    const float* Abase = A + (size_t)row0 * 64;
    int maxElems = (N - row0) * 64;
#pragma unroll
    for (int p = 0; p < 4; ++p) {
        int idx = t + p * 256;
        int r = idx >> 4, k0 = (idx & 15) << 2;
        float4 v = make_float4(0.f, 0.f, 0.f, 0.f);
        if (idx * 4 < maxElems) v = *reinterpret_cast<const float4*>(Abase + (size_t)idx * 4);
        *reinterpret_cast<float4*>(&As[r][k0]) = v;
    }
#pragma unroll
    for (int p = 0; p < 4; ++p) {
        int idx = t + p * 256;
        int k = idx >> 4, cc = (idx & 15) << 2;
        float4 v = *reinterpret_cast<const float4*>(&B[(size_t)k * C + col0 + cc]);
        *reinterpret_cast<float4*>(&Bs[k][cc]) = v;
    }
    __syncthreads();

    int c0 = (t & 15) * 4;
    int r0 = (t >> 4) * 4;
    float4 acc[4];
#pragma unroll
    for (int i = 0; i < 4; ++i) acc[i] = make_float4(0.f, 0.f, 0.f, 0.f);

#pragma unroll 2
    for (int k0 = 0; k0 < 64; k0 += 4) {
        float4 a[4], b[4];
#pragma unroll
        for (int i = 0; i < 4; ++i) a[i] = *reinterpret_cast<const float4*>(&As[r0 + i][k0]);
#pragma unroll
        for (int j = 0; j < 4; ++j) b[j] = *reinterpret_cast<const float4*>(&Bs[k0 + j][c0]);
#pragma unroll
        for (int i = 0; i < 4; ++i) {
            acc[i].x += a[i].x * b[0].x + a[i].y * b[1].x + a[i].z * b[2].x + a[i].w * b[3].x;
            acc[i].y += a[i].x * b[0].y + a[i].y * b[1].y + a[i].z * b[2].y + a[i].w * b[3].y;
            acc[i].z += a[i].x * b[0].z + a[i].y * b[1].z + a[i].z * b[2].z + a[i].w * b[3].z;
            acc[i].w += a[i].x * b[0].w + a[i].y * b[1].w + a[i].z * b[2].w + a[i].w * b[3].w;
        }
    }

    float4 bv = *reinterpret_cast<const float4*>(&bias[col0 + c0]);
#pragma unroll
    for (int i = 0; i < 4; ++i) {
        int row = row0 + r0 + i;
        if (row < N) {
            float4 o;
            o.x = fmaxf(acc[i].x + bv.x, 0.f);
            o.y = fmaxf(acc[i].y + bv.y, 0.f);
            o.z = fmaxf(acc[i].z + bv.z, 0.f);
            o.w = fmaxf(acc[i].w + bv.w, 0.f);
            *reinterpret_cast<float4*>(&out[(size_t)row * C + col0 + c0]) = o;
        }
    }
}

// ---------- per-graph column max, no atomics: grid (32 graphs, 8 splits), 128 thr ----------
__global__ __launch_bounds__(128) void graph_max(const float* __restrict__ rst2,
                                                 const int* __restrict__ gstart,
                                                 float* __restrict__ gm) {
    int g = blockIdx.x, sp = blockIdx.y;
    int t = threadIdx.x;  // column 0..127
    int rb = gstart[g], re = gstart[g + 1];
    float m = -INFINITY;
    for (int r = rb + sp; r < re; r += 8)
        m = fmaxf(m, rst2[(size_t)r * 128 + t]);
    gm[(size_t)sp * 4096 + g * 128 + t] = m;
}

// ---------- head MLP: folds the 8 graph-max partials ----------
__global__ void mlp_head(const float* __restrict__ gml, const float* __restrict__ gmr,
                         const float* __restrict__ W1, const float* __restrict__ b1,
                         const float* __restrict__ W2, const float* __restrict__ b2,
                         float* __restrict__ out) {
    __shared__ float hcat[32][256];
    __shared__ float h[32][128];
    int t = threadIdx.x;  // 256 threads
    for (int i = t; i < 32 * 128; i += 256) {
        int r = i / 128, c = i % 128;
        float ml = -INFINITY, mr = -INFINITY;
#pragma unroll
        for (int sp = 0; sp < 8; ++sp) {
            ml = fmaxf(ml, gml[sp * 4096 + i]);
            mr = fmaxf(mr, gmr[sp * 4096 + i]);
        }
        // relu outputs are >=0, so fmax(m,0) == (isfinite(m) ? m : 0)
        hcat[r][c] = fmaxf(ml, 0.f);
        hcat[r][128 + c] = fmaxf(mr, 0.f);
    }
    __syncthreads();
    for (int i = t; i < 32 * 128; i += 256) {
        int r = i / 128, c = i % 128;
        float acc = b1[c];
        for (int k = 0; k < 256; ++k) acc += hcat[r][k] * W1[k * 128 + c];
        h[r][c] = acc > 0.f ? acc : 0.f;
    }
    __syncthreads();
    if (t < 32) {
        float acc = b2[0];
        for (int k = 0; k < 128; ++k) acc += h[t][k] * W2[k];
        out[t] = acc > 0.f ? acc : 0.f;
    }
}

// ---------- launch ----------
static inline unsigned nblk_elem(long long total) {
    long long b = (total + 255) / 256;
    if (b > 65535) b = 65535;
    if (b < 1) b = 1;
    return (unsigned)b;
}
static inline unsigned nblk_gather(long long nodes) {
    long long b = (nodes + 3) / 4;
    if (b > 65535) b = 65535;
    if (b < 1) b = 1;
    return (unsigned)b;
}

extern "C" void kernel_launch(void* const* d_in, const int* in_sizes, int n_in,
                              void* d_out, int out_size, void* d_ws, size_t ws_size,
                              hipStream_t stream) {
    const float* lig_x = (const float*)d_in[0];
    const int* lig_src = (const int*)d_in[1];
    const int* lig_dst = (const int*)d_in[2];
    const int* lig_gid = (const int*)d_in[3];
    const float* rec_x = (const float*)d_in[4];
    const int* rec_src = (const int*)d_in[5];
    const int* rec_dst = (const int*)d_in[6];
    const int* rec_gid = (const int*)d_in[7];
    const float* W1l = (const float*)d_in[8];
    const float* al1l = (const float*)d_in[9];
    const float* ar1l = (const float*)d_in[10];
    const float* b1l = (const float*)d_in[11];
    const float* W2l = (const float*)d_in[12];
    const float* al2l = (const float*)d_in[13];
    const float* ar2l = (const float*)d_in[14];
    const float* b2l = (const float*)d_in[15];
    const float* W1r = (const float*)d_in[16];
    const float* al1r = (const float*)d_in[17];
    const float* ar1r = (const float*)d_in[18];
    const float* b1r = (const float*)d_in[19];
    const float* W2r = (const float*)d_in[20];
    const float* al2r = (const float*)d_in[21];
    const float* ar2r = (const float*)d_in[22];
    const float* b2r = (const float*)d_in[23];
    const float* Wlin1 = (const float*)d_in[24];
    const float* blin1 = (const float*)d_in[25];
    const float* Wlin2 = (const float*)d_in[26];
    const float* blin2 = (const float*)d_in[27];

    int Nl = in_sizes[0] / 64, El = in_sizes[1];
    int Nr = in_sizes[4] / 64, Er = in_sizes[5];
    long long Nmax = Nl > Nr ? Nl : Nr;
    long long Emax = El > Er ? El : Er;

    // workspace layout
    char* ws = (char*)d_ws;
    float* z = (float*)ws;           ws += Nmax * 640 * 4;  // layer1 z; layer2 z2+rst2 alias
    float* h1 = (float*)ws;          ws += Nmax * 64 * 4;
    float* elb = (float*)ws;         ws += Nmax * 10 * 4;
    float* erb = (float*)ws;         ws += Nmax * 10 * 4;
    int* deg = (int*)ws;             ws += Nmax * 4;
    int* cursor = (int*)ws;          ws += Nmax * 4;
    int* rowptr = (int*)ws;          ws += (Nmax + 1) * 4;
    int* adj = (int*)ws;             ws += Emax * 4;
    int* dslot = (int*)ws;           ws += Emax * 4;
    float* ebuf = (float*)ws;        ws += Emax * 10 * 4;
    float* alpha = (float*)ws;       ws += Emax * 10 * 4;
    float* gml = (float*)ws;         ws += 8 * 32 * 128 * 4;
    float* gmr = (float*)ws;         ws += 8 * 32 * 128 * 4;
    float* Walr = (float*)ws;        ws += 64 * 32 * 4;
    int* gstart = (int*)ws;          ws += 40 * 4;
    float* z2 = z;                    // [N,64] (z free after gemm_heads)
    float* rst2 = z + Nmax * 64;      // [N,128] (disjoint from z2)

    auto run_branch = [&](const float* x, const int* src, const int* dst, const int* gid,
                          const float* W1, const float* al1, const float* ar1, const float* b1,
                          const float* W2, const float* al2, const float* ar2, const float* b2,
                          float* gm, int N, int E) {
        // CSR + graph boundaries (shared by both layers)
        hipMemsetAsync(deg, 0, (size_t)N * 4, stream);
        count_deg<<<nblk_elem(E), 256, 0, stream>>>(dst, deg, E);
        build_rowptr<<<1, 1024, 0, stream>>>(deg, rowptr, N);
        hipMemcpyAsync(cursor, rowptr, (size_t)N * 4, hipMemcpyDeviceToDevice, stream);
        fill_adj<<<nblk_elem(E), 256, 0, stream>>>(src, dst, cursor, adj, dslot, E);
        gstart_build<<<nblk_elem(N), 256, 0, stream>>>(gid, gstart, N, 32);

        // ---- layer 1: H=10, aggregate x then project ----
        fold_attn<<<64, 64, 0, stream>>>(W1, al1, ar1, Walr, 10, 64);
        attn_from_x<<<nblk_gather(N), 256, 0, stream>>>(x, Walr, elb, erb, N, 10);
        edge_e<10><<<nblk_elem(E), 256, 0, stream>>>(adj, dslot, elb, erb, ebuf, E);
        node_norm<10><<<nblk_elem(N), 256, 0, stream>>>(rowptr, ebuf, alpha, N);
        gather_z<10><<<nblk_gather(N), 256, 0, stream>>>(rowptr, adj, alpha, x, z, N);
        gemm_heads<10><<<(N + 63) / 64, 256, 0, stream>>>(z, W1, b1, h1, N);

        // ---- layer 2: H=1, aggregate h1 then project, then atomic-free graph max ----
        fold_attn<<<64, 64, 0, stream>>>(W2, al2, ar2, Walr, 1, 128);
        attn_from_x<<<nblk_gather(N), 256, 0, stream>>>(h1, Walr, elb, erb, N, 1);
        edge_e<1><<<nblk_elem(E), 256, 0, stream>>>(adj, dslot, elb, erb, ebuf, E);
        node_norm<1><<<nblk_elem(N), 256, 0, stream>>>(rowptr, ebuf, alpha, N);
        gather_z<1><<<nblk_gather(N), 256, 0, stream>>>(rowptr, adj, alpha, h1, z2, N);
        gemm_relu<<<dim3((N + 63) / 64, 2), 256, 0, stream>>>(z2, W2, b2, rst2, N);
        graph_max<<<dim3(32, 8), 128, 0, stream>>>(rst2, gstart, gm);
    };

    run_branch(lig_x, lig_src, lig_dst, lig_gid, W1l, al1l, ar1l, b1l, W2l, al2l, ar2l, b2l,
               gml, Nl, El);
    run_branch(rec_x, rec_src, rec_dst, rec_gid, W1r, al1r, ar1r, b1r, W2r, al2r, ar2r, b2r,
               gmr, Nr, Er);

    mlp_head<<<1, 256, 0, stream>>>(gml, gmr, Wlin1, blin1, Wlin2, blin2, (float*)d_out);
}

// Round 9
// 655.087 us; speedup vs baseline: 1.5690x; 1.1030x over previous
//
#include <hip/hip_runtime.h>
#include <hip/hip_bf16.h>

typedef short bf16x8 __attribute__((ext_vector_type(8)));
typedef float f32x4 __attribute__((ext_vector_type(4)));

__device__ inline float lrelu(float x) { return x > 0.f ? x : 0.2f * x; }

// fp32 -> bf16 (round-to-nearest-even)
__device__ inline unsigned short f2bf(float f) {
    unsigned u = __float_as_uint(f);
    u = u + 0x7FFFu + ((u >> 16) & 1u);
    return (unsigned short)(u >> 16);
}

// ---------- fold attention vectors through W: Walr[k][2H] ----------
__global__ void fold_attn(const float* __restrict__ W, const float* __restrict__ al,
                          const float* __restrict__ ar, float* __restrict__ Walr,
                          int H, int D) {
    int k = blockIdx.x;
    int lane = threadIdx.x;
    int C = H * D;
    for (int h = 0; h < H; ++h) {
        float sl = 0.f, sr = 0.f;
        for (int d = lane; d < D; d += 64) {
            float w = W[(size_t)k * C + h * D + d];
            sl += w * al[h * D + d];
            sr += w * ar[h * D + d];
        }
        for (int off = 32; off; off >>= 1) {
            sl += __shfl_down(sl, off);
            sr += __shfl_down(sr, off);
        }
        if (lane == 0) {
            Walr[k * 2 * H + h] = sl;
            Walr[k * 2 * H + H + h] = sr;
        }
    }
}

// ---------- el/er from 64-dim input: one wave per node ----------
__global__ void attn_from_x(const float* __restrict__ in, const float* __restrict__ Walr,
                            float* __restrict__ el, float* __restrict__ er, int N, int H) {
    int lane = threadIdx.x & 63;
    int wib = threadIdx.x >> 6;
    int wpb = blockDim.x >> 6;
    int wstride = gridDim.x * wpb;
    int H2 = 2 * H;
    for (int n = blockIdx.x * wpb + wib; n < N; n += wstride) {
        float x = in[(size_t)n * 64 + lane];
        const float* wrow = Walr + lane * H2;
        for (int h = 0; h < H2; ++h) {
            float s = x * wrow[h];
            for (int off = 32; off; off >>= 1) s += __shfl_down(s, off);
            if (lane == 0) {
                if (h < H) el[(size_t)n * H + h] = s;
                else       er[(size_t)n * H + h - H] = s;
            }
        }
    }
}

// ---------- CSR build ----------
__global__ void count_deg(const int* __restrict__ dst, int* __restrict__ deg, int E) {
    int stride = gridDim.x * blockDim.x;
    for (int i = blockIdx.x * blockDim.x + threadIdx.x; i < E; i += stride)
        atomicAdd(&deg[dst[i]], 1);
}

__global__ void build_rowptr(const int* __restrict__ deg, int* __restrict__ rowptr, int N) {
    __shared__ int ssum[1024];
    int t = threadIdx.x;
    int nt = blockDim.x;
    int chunk = (N + nt - 1) / nt;
    int beg = t * chunk;
    int end = beg + chunk; if (end > N) end = N; if (beg > N) beg = N;
    int s = 0;
    for (int i = beg; i < end; ++i) s += deg[i];
    ssum[t] = s;
    __syncthreads();
    for (int off = 1; off < nt; off <<= 1) {
        int v = (t >= off) ? ssum[t - off] : 0;
        __syncthreads();
        ssum[t] += v;
        __syncthreads();
    }
    int run = (t == 0) ? 0 : ssum[t - 1];
    for (int i = beg; i < end; ++i) { rowptr[i] = run; run += deg[i]; }
    if (t == nt - 1) rowptr[N] = run;
}

__global__ void fill_adj(const int* __restrict__ src, const int* __restrict__ dst,
                         int* __restrict__ cursor, int* __restrict__ adj,
                         int* __restrict__ dslot, int E) {
    int stride = gridDim.x * blockDim.x;
    for (int i = blockIdx.x * blockDim.x + threadIdx.x; i < E; i += stride) {
        int d = dst[i];
        int pos = atomicAdd(&cursor[d], 1);
        adj[pos] = src[i];
        dslot[pos] = d;
    }
}

// ---------- graph segment boundaries from SORTED gid ----------
__global__ void gstart_build(const int* __restrict__ gid, int* __restrict__ gstart,
                             int N, int NG) {
    int stride = gridDim.x * blockDim.x;
    for (int n = blockIdx.x * blockDim.x + threadIdx.x; n < N; n += stride) {
        int gcur = gid[n];
        int gprev = (n == 0) ? -1 : gid[n - 1];
        for (int g = gprev + 1; g <= gcur; ++g) gstart[g] = n;
        if (n == N - 1)
            for (int g = gcur + 1; g <= NG; ++g) gstart[g] = N;
    }
}

// ---------- per-slot raw attention logits ----------
template <int H>
__global__ void edge_e(const int* __restrict__ adj, const int* __restrict__ dslot,
                       const float* __restrict__ el, const float* __restrict__ er,
                       float* __restrict__ e, int E) {
    int stride = gridDim.x * blockDim.x;
    for (int i = blockIdx.x * blockDim.x + threadIdx.x; i < E; i += stride) {
        int s = adj[i], d = dslot[i];
        const float* els = el + (size_t)s * H;
        const float* erd = er + (size_t)d * H;
#pragma unroll
        for (int h = 0; h < H; ++h)
            e[(size_t)i * H + h] = lrelu(els[h] + erd[h]);
    }
}

// ---------- per-node softmax normalize ----------
template <int H>
__global__ void node_norm(const int* __restrict__ rowptr, const float* __restrict__ e,
                          float* __restrict__ alpha, int N) {
    int stride = gridDim.x * blockDim.x;
    for (int n = blockIdx.x * blockDim.x + threadIdx.x; n < N; n += stride) {
        int rbeg = rowptr[n], rend = rowptr[n + 1];
        if (rbeg == rend) continue;
        float m[H], den[H];
#pragma unroll
        for (int h = 0; h < H; ++h) { m[h] = -INFINITY; den[h] = 0.f; }
        for (int j = rbeg; j < rend; ++j) {
#pragma unroll
            for (int h = 0; h < H; ++h) {
                float ev = e[(size_t)j * H + h];
                float newm = fmaxf(m[h], ev);
                den[h] = den[h] * __expf(m[h] - newm) + __expf(ev - newm);
                m[h] = newm;
            }
        }
        float inv[H];
#pragma unroll
        for (int h = 0; h < H; ++h) inv[h] = 1.f / fmaxf(den[h], 1e-9f);
        for (int j = rbeg; j < rend; ++j) {
#pragma unroll
            for (int h = 0; h < H; ++h)
                alpha[(size_t)j * H + h] = __expf(e[(size_t)j * H + h] - m[h]) * inv[h];
        }
    }
}

// ---------- gather RAW input rows weighted by alpha ----------
template <int H>
__global__ __launch_bounds__(256, 8) void gather_z(
        const int* __restrict__ rowptr, const int* __restrict__ adj,
        const float* __restrict__ alpha, const float* __restrict__ x,
        float* __restrict__ z, int N) {
    int lane = threadIdx.x & 63;
    int w = threadIdx.x >> 6;
    int wpb = blockDim.x >> 6;
    int wstride = gridDim.x * wpb;
    for (int n = blockIdx.x * wpb + w; n < N; n += wstride) {
        int rbeg = __builtin_amdgcn_readfirstlane(rowptr[n]);
        int rend = __builtin_amdgcn_readfirstlane(rowptr[n + 1]);
        float acc[H];
#pragma unroll
        for (int h = 0; h < H; ++h) acc[h] = 0.f;
        for (int j = rbeg; j < rend; ++j) {
            int s = __builtin_amdgcn_readfirstlane(adj[j]);
            float xv = x[(size_t)s * 64 + lane];
            const float* al = alpha + (size_t)j * H;
#pragma unroll
            for (int h = 0; h < H; ++h) acc[h] += al[h] * xv;
        }
#pragma unroll
        for (int h = 0; h < H; ++h)
            z[(size_t)n * (H * 64) + h * 64 + lane] = acc[h];
    }
}

// ---------- pack W[64][C] into per-lane bf16 MFMA B-fragments ----------
// F flat index: (((CT*2 + step)*64 + lane)*8 + j), CT = global 16-col tile.
// value = bf16( W[k][CT*16 + (lane&15)] ), k = (lane>>4)*8 + j + step*32.
__global__ void prep_wfrag(const float* __restrict__ W, unsigned short* __restrict__ F,
                           int C) {
    int total = (C >> 4) * 1024;
    int stride = gridDim.x * blockDim.x;
    for (int idx = blockIdx.x * blockDim.x + threadIdx.x; idx < total; idx += stride) {
        int j = idx & 7;
        int lane = (idx >> 3) & 63;
        int step = (idx >> 9) & 1;
        int CT = idx >> 10;
        int k = ((lane >> 4) << 3) + j + (step << 5);
        int col = (CT << 4) + (lane & 15);
        F[idx] = f2bf(W[(size_t)k * C + col]);
    }
}

// ---------- MFMA per-head projection + relu + head-sum ----------
// out[n][0..63] = sum_h relu( z[n, h*64:(h+1)*64] @ W_h + bias_h )
// block = 256 thr (4 waves), each wave: 16 rows x 64 cols. No LDS, no barriers.
template <int H>
__global__ __launch_bounds__(256) void gemm_heads_mfma(
        const float* __restrict__ z, const bf16x8* __restrict__ Wf,
        const float* __restrict__ bias, float* __restrict__ out, int N) {
    const int SA = H * 64;
    int lane = threadIdx.x & 63;
    int w = threadIdx.x >> 6;
    int row0 = blockIdx.x * 64 + w * 16;
    int arow = row0 + (lane & 15);
    if (arow > N - 1) arow = N - 1;      // clamp loads; stores masked by real row
    int kb = (lane >> 4) * 8;
    int colL = lane & 15;

    f32x4 o0 = {0,0,0,0}, o1 = {0,0,0,0}, o2 = {0,0,0,0}, o3 = {0,0,0,0};

    for (int h = 0; h < H; ++h) {
        const float* zr = z + (size_t)arow * SA + h * 64 + kb;
        float4 a0 = *reinterpret_cast<const float4*>(zr);
        float4 a1 = *reinterpret_cast<const float4*>(zr + 4);
        float4 a2 = *reinterpret_cast<const float4*>(zr + 32);
        float4 a3 = *reinterpret_cast<const float4*>(zr + 36);
        bf16x8 A0, A1;
        A0[0] = (short)f2bf(a0.x); A0[1] = (short)f2bf(a0.y);
        A0[2] = (short)f2bf(a0.z); A0[3] = (short)f2bf(a0.w);
        A0[4] = (short)f2bf(a1.x); A0[5] = (short)f2bf(a1.y);
        A0[6] = (short)f2bf(a1.z); A0[7] = (short)f2bf(a1.w);
        A1[0] = (short)f2bf(a2.x); A1[1] = (short)f2bf(a2.y);
        A1[2] = (short)f2bf(a2.z); A1[3] = (short)f2bf(a2.w);
        A1[4] = (short)f2bf(a3.x); A1[5] = (short)f2bf(a3.y);
        A1[6] = (short)f2bf(a3.z); A1[7] = (short)f2bf(a3.w);

        f32x4 acc0 = {0,0,0,0}, acc1 = {0,0,0,0}, acc2 = {0,0,0,0}, acc3 = {0,0,0,0};
#define CT_STEP(accv, ct)                                                            \
        {                                                                            \
            bf16x8 B0 = Wf[((h * 4 + (ct)) * 2 + 0) * 64 + lane];                    \
            bf16x8 B1 = Wf[((h * 4 + (ct)) * 2 + 1) * 64 + lane];                    \
            accv = __builtin_amdgcn_mfma_f32_16x16x32_bf16(A0, B0, accv, 0, 0, 0);   \
            accv = __builtin_amdgcn_mfma_f32_16x16x32_bf16(A1, B1, accv, 0, 0, 0);   \
        }
        CT_STEP(acc0, 0) CT_STEP(acc1, 1) CT_STEP(acc2, 2) CT_STEP(acc3, 3)
#undef CT_STEP

#define EPI(ov, accv, ct)                                                            \
        {                                                                            \
            float bv = bias[h * 64 + (ct) * 16 + colL];                              \
            ov[0] += fmaxf(accv[0] + bv, 0.f);                                       \
            ov[1] += fmaxf(accv[1] + bv, 0.f);                                       \
            ov[2] += fmaxf(accv[2] + bv, 0.f);                                       \
            ov[3] += fmaxf(accv[3] + bv, 0.f);                                       \
        }
        EPI(o0, acc0, 0) EPI(o1, acc1, 1) EPI(o2, acc2, 2) EPI(o3, acc3, 3)
#undef EPI
    }

    int rbase = row0 + (lane >> 4) * 4;
#define ST(ov, ct)                                                                   \
    {                                                                                \
        _Pragma("unroll")                                                            \
        for (int r = 0; r < 4; ++r) {                                                \
            int row = rbase + r;                                                     \
            if (row < N) out[(size_t)row * 64 + (ct) * 16 + colL] = ov[r];           \
        }                                                                            \
    }
    ST(o0, 0) ST(o1, 1) ST(o2, 2) ST(o3, 3)
#undef ST
}

// ---------- MFMA layer-2 GEMM: rst2 = relu(z2[N,64] @ W2[64,128] + bias) ----------
// block = 256 thr (4 waves), each wave: 16 rows x 128 cols (8 col-tiles).
__global__ __launch_bounds__(256) void gemm_relu_mfma(
        const float* __restrict__ z, const bf16x8* __restrict__ Wf,
        const float* __restrict__ bias, float* __restrict__ out, int N) {
    int lane = threadIdx.x & 63;
    int w = threadIdx.x >> 6;
    int row0 = blockIdx.x * 64 + w * 16;
    int arow = row0 + (lane & 15);
    if (arow > N - 1) arow = N - 1;
    int kb = (lane >> 4) * 8;
    int colL = lane & 15;

    const float* zr = z + (size_t)arow * 64 + kb;
    float4 a0 = *reinterpret_cast<const float4*>(zr);
    float4 a1 = *reinterpret_cast<const float4*>(zr + 4);
    float4 a2 = *reinterpret_cast<const float4*>(zr + 32);
    float4 a3 = *reinterpret_cast<const float4*>(zr + 36);
    bf16x8 A0, A1;
    A0[0] = (short)f2bf(a0.x); A0[1] = (short)f2bf(a0.y);
    A0[2] = (short)f2bf(a0.z); A0[3] = (short)f2bf(a0.w);
    A0[4] = (short)f2bf(a1.x); A0[5] = (short)f2bf(a1.y);
    A0[6] = (short)f2bf(a1.z); A0[7] = (short)f2bf(a1.w);
    A1[0] = (short)f2bf(a2.x); A1[1] = (short)f2bf(a2.y);
    A1[2] = (short)f2bf(a2.z); A1[3] = (short)f2bf(a2.w);
    A1[4] = (short)f2bf(a3.x); A1[5] = (short)f2bf(a3.y);
    A1[6] = (short)f2bf(a3.z); A1[7] = (short)f2bf(a3.w);

    int rbase = row0 + (lane >> 4) * 4;
#define DO_CT(ct)                                                                    \
    {                                                                                \
        bf16x8 B0 = Wf[((ct) * 2 + 0) * 64 + lane];                                  \
        bf16x8 B1 = Wf[((ct) * 2 + 1) * 64 + lane];                                  \
        f32x4 acc = {0, 0, 0, 0};                                                    \
        acc = __builtin_amdgcn_mfma_f32_16x16x32_bf16(A0, B0, acc, 0, 0, 0);         \
        acc = __builtin_amdgcn_mfma_f32_16x16x32_bf16(A1, B1, acc, 0, 0, 0);         \
        float bv = bias[(ct) * 16 + colL];                                           \
        _Pragma("unroll")                                                            \
        for (int r = 0; r < 4; ++r) {                                                \
            int row = rbase + r;                                                     \
            if (row < N)                                                             \
                out[(size_t)row * 128 + (ct) * 16 + colL] = fmaxf(acc[r] + bv, 0.f); \
        }                                                                            \
    }
    DO_CT(0) DO_CT(1) DO_CT(2) DO_CT(3) DO_CT(4) DO_CT(5) DO_CT(6) DO_CT(7)
#undef DO_CT
}

// ---------- per-graph column max, no atomics ----------
__global__ __launch_bounds__(128) void graph_max(const float* __restrict__ rst2,
                                                 const int* __restrict__ gstart,
                                                 float* __restrict__ gm) {
    int g = blockIdx.x, sp = blockIdx.y;
    int t = threadIdx.x;
    int rb = gstart[g], re = gstart[g + 1];
    float m = -INFINITY;
    for (int r = rb + sp; r < re; r += 8)
        m = fmaxf(m, rst2[(size_t)r * 128 + t]);
    gm[(size_t)sp * 4096 + g * 128 + t] = m;
}

// ---------- head MLP ----------
__global__ void mlp_head(const float* __restrict__ gml, const float* __restrict__ gmr,
                         const float* __restrict__ W1, const float* __restrict__ b1,
                         const float* __restrict__ W2, const float* __restrict__ b2,
                         float* __restrict__ out) {
    __shared__ float hcat[32][256];
    __shared__ float h[32][128];
    int t = threadIdx.x;
    for (int i = t; i < 32 * 128; i += 256) {
        int r = i / 128, c = i % 128;
        float ml = -INFINITY, mr = -INFINITY;
#pragma unroll
        for (int sp = 0; sp < 8; ++sp) {
            ml = fmaxf(ml, gml[sp * 4096 + i]);
            mr = fmaxf(mr, gmr[sp * 4096 + i]);
        }
        hcat[r][c] = fmaxf(ml, 0.f);
        hcat[r][128 + c] = fmaxf(mr, 0.f);
    }
    __syncthreads();
    for (int i = t; i < 32 * 128; i += 256) {
        int r = i / 128, c = i % 128;
        float acc = b1[c];
        for (int k = 0; k < 256; ++k) acc += hcat[r][k] * W1[k * 128 + c];
        h[r][c] = acc > 0.f ? acc : 0.f;
    }
    __syncthreads();
    if (t < 32) {
        float acc = b2[0];
        for (int k = 0; k < 128; ++k) acc += h[t][k] * W2[k];
        out[t] = acc > 0.f ? acc : 0.f;
    }
}

// ---------- launch ----------
static inline unsigned nblk_elem(long long total) {
    long long b = (total + 255) / 256;
    if (b > 65535) b = 65535;
    if (b < 1) b = 1;
    return (unsigned)b;
}
static inline unsigned nblk_gather(long long nodes) {
    long long b = (nodes + 3) / 4;
    if (b > 65535) b = 65535;
    if (b < 1) b = 1;
    return (unsigned)b;
}

extern "C" void kernel_launch(void* const* d_in, const int* in_sizes, int n_in,
                              void* d_out, int out_size, void* d_ws, size_t ws_size,
                              hipStream_t stream) {
    const float* lig_x = (const float*)d_in[0];
    const int* lig_src = (const int*)d_in[1];
    const int* lig_dst = (const int*)d_in[2];
    const int* lig_gid = (const int*)d_in[3];
    const float* rec_x = (const float*)d_in[4];
    const int* rec_src = (const int*)d_in[5];
    const int* rec_dst = (const int*)d_in[6];
    const int* rec_gid = (const int*)d_in[7];
    const float* W1l = (const float*)d_in[8];
    const float* al1l = (const float*)d_in[9];
    const float* ar1l = (const float*)d_in[10];
    const float* b1l = (const float*)d_in[11];
    const float* W2l = (const float*)d_in[12];
    const float* al2l = (const float*)d_in[13];
    const float* ar2l = (const float*)d_in[14];
    const float* b2l = (const float*)d_in[15];
    const float* W1r = (const float*)d_in[16];
    const float* al1r = (const float*)d_in[17];
    const float* ar1r = (const float*)d_in[18];
    const float* b1r = (const float*)d_in[19];
    const float* W2r = (const float*)d_in[20];
    const float* al2r = (const float*)d_in[21];
    const float* ar2r = (const float*)d_in[22];
    const float* b2r = (const float*)d_in[23];
    const float* Wlin1 = (const float*)d_in[24];
    const float* blin1 = (const float*)d_in[25];
    const float* Wlin2 = (const float*)d_in[26];
    const float* blin2 = (const float*)d_in[27];

    int Nl = in_sizes[0] / 64, El = in_sizes[1];
    int Nr = in_sizes[4] / 64, Er = in_sizes[5];
    long long Nmax = Nl > Nr ? Nl : Nr;
    long long Emax = El > Er ? El : Er;

    // workspace layout
    char* ws = (char*)d_ws;
    float* z = (float*)ws;           ws += Nmax * 640 * 4;  // layer1 z; layer2 z2+rst2 alias
    float* h1 = (float*)ws;          ws += Nmax * 64 * 4;
    float* elb = (float*)ws;         ws += Nmax * 10 * 4;
    float* erb = (float*)ws;         ws += Nmax * 10 * 4;
    int* deg = (int*)ws;             ws += Nmax * 4;
    int* cursor = (int*)ws;          ws += Nmax * 4;
    int* rowptr = (int*)ws;          ws += (Nmax + 1) * 4;
    int* adj = (int*)ws;             ws += Emax * 4;
    int* dslot = (int*)ws;           ws += Emax * 4;
    float* ebuf = (float*)ws;        ws += Emax * 10 * 4;
    float* alpha = (float*)ws;       ws += Emax * 10 * 4;
    float* gml = (float*)ws;         ws += 8 * 32 * 128 * 4;
    float* gmr = (float*)ws;         ws += 8 * 32 * 128 * 4;
    float* Walr = (float*)ws;        ws += 64 * 32 * 4;
    int* gstart = (int*)ws;          ws += 40 * 4;
    unsigned short* wf1 = (unsigned short*)ws;  ws += 40960 * 2;  // W1 fragments
    unsigned short* wf2 = (unsigned short*)ws;  ws += 8192 * 2;   // W2 fragments
    float* z2 = z;                    // [N,64]
    float* rst2 = z + Nmax * 64;      // [N,128]

    auto run_branch = [&](const float* x, const int* src, const int* dst, const int* gid,
                          const float* W1, const float* al1, const float* ar1, const float* b1,
                          const float* W2, const float* al2, const float* ar2, const float* b2,
                          float* gm, int N, int E) {
        // CSR + graph boundaries + weight fragments
        hipMemsetAsync(deg, 0, (size_t)N * 4, stream);
        count_deg<<<nblk_elem(E), 256, 0, stream>>>(dst, deg, E);
        build_rowptr<<<1, 1024, 0, stream>>>(deg, rowptr, N);
        hipMemcpyAsync(cursor, rowptr, (size_t)N * 4, hipMemcpyDeviceToDevice, stream);
        fill_adj<<<nblk_elem(E), 256, 0, stream>>>(src, dst, cursor, adj, dslot, E);
        gstart_build<<<nblk_elem(N), 256, 0, stream>>>(gid, gstart, N, 32);
        prep_wfrag<<<40, 256, 0, stream>>>(W1, wf1, 640);
        prep_wfrag<<<8, 256, 0, stream>>>(W2, wf2, 128);

        // ---- layer 1: H=10, aggregate x then project (MFMA) ----
        fold_attn<<<64, 64, 0, stream>>>(W1, al1, ar1, Walr, 10, 64);
        attn_from_x<<<nblk_gather(N), 256, 0, stream>>>(x, Walr, elb, erb, N, 10);
        edge_e<10><<<nblk_elem(E), 256, 0, stream>>>(adj, dslot, elb, erb, ebuf, E);
        node_norm<10><<<nblk_elem(N), 256, 0, stream>>>(rowptr, ebuf, alpha, N);
        gather_z<10><<<nblk_gather(N), 256, 0, stream>>>(rowptr, adj, alpha, x, z, N);
        gemm_heads_mfma<10><<<(N + 63) / 64, 256, 0, stream>>>(z, (const bf16x8*)wf1, b1, h1, N);

        // ---- layer 2: H=1, aggregate h1 then project (MFMA), atomic-free graph max ----
        fold_attn<<<64, 64, 0, stream>>>(W2, al2, ar2, Walr, 1, 128);
        attn_from_x<<<nblk_gather(N), 256, 0, stream>>>(h1, Walr, elb, erb, N, 1);
        edge_e<1><<<nblk_elem(E), 256, 0, stream>>>(adj, dslot, elb, erb, ebuf, E);
        node_norm<1><<<nblk_elem(N), 256, 0, stream>>>(rowptr, ebuf, alpha, N);
        gather_z<1><<<nblk_gather(N), 256, 0, stream>>>(rowptr, adj, alpha, h1, z2, N);
        gemm_relu_mfma<<<(N + 63) / 64, 256, 0, stream>>>(z2, (const bf16x8*)wf2, b2, rst2, N);
        graph_max<<<dim3(32, 8), 128, 0, stream>>>(rst2, gstart, gm);
    };

    run_branch(lig_x, lig_src, lig_dst, lig_gid, W1l, al1l, ar1l, b1l, W2l, al2l, ar2l, b2l,
               gml, Nl, El);
    run_branch(rec_x, rec_src, rec_dst, rec_gid, W1r, al1r, ar1r, b1r, W2r, al2r, ar2r, b2r,
               gmr, Nr, Er);

    mlp_head<<<1, 256, 0, stream>>>(gml, gmr, Wlin1, blin1, Wlin2, blin2, (float*)d_out);
}

// Round 10
// 582.110 us; speedup vs baseline: 1.7657x; 1.1254x over previous
//
#include <hip/hip_runtime.h>
#include <hip/hip_bf16.h>

typedef short bf16x8 __attribute__((ext_vector_type(8)));
typedef float f32x4 __attribute__((ext_vector_type(4)));

__device__ inline float lrelu(float x) { return x > 0.f ? x : 0.2f * x; }

// fp32 -> bf16 (round-to-nearest-even)
__device__ inline unsigned short f2bf(float f) {
    unsigned u = __float_as_uint(f);
    u = u + 0x7FFFu + ((u >> 16) & 1u);
    return (unsigned short)(u >> 16);
}

// ---------- fold attention vectors through W: Walr[k][2H] ----------
__global__ void fold_attn(const float* __restrict__ W, const float* __restrict__ al,
                          const float* __restrict__ ar, float* __restrict__ Walr,
                          int H, int D) {
    int k = blockIdx.x;
    int lane = threadIdx.x;
    int C = H * D;
    for (int h = 0; h < H; ++h) {
        float sl = 0.f, sr = 0.f;
        for (int d = lane; d < D; d += 64) {
            float w = W[(size_t)k * C + h * D + d];
            sl += w * al[h * D + d];
            sr += w * ar[h * D + d];
        }
        for (int off = 32; off; off >>= 1) {
            sl += __shfl_down(sl, off);
            sr += __shfl_down(sr, off);
        }
        if (lane == 0) {
            Walr[k * 2 * H + h] = sl;
            Walr[k * 2 * H + H + h] = sr;
        }
    }
}

// ---------- el/er from 64-dim input: one wave per node ----------
__global__ void attn_from_x(const float* __restrict__ in, const float* __restrict__ Walr,
                            float* __restrict__ el, float* __restrict__ er, int N, int H) {
    int lane = threadIdx.x & 63;
    int wib = threadIdx.x >> 6;
    int wpb = blockDim.x >> 6;
    int wstride = gridDim.x * wpb;
    int H2 = 2 * H;
    for (int n = blockIdx.x * wpb + wib; n < N; n += wstride) {
        float x = in[(size_t)n * 64 + lane];
        const float* wrow = Walr + lane * H2;
        for (int h = 0; h < H2; ++h) {
            float s = x * wrow[h];
            for (int off = 32; off; off >>= 1) s += __shfl_down(s, off);
            if (lane == 0) {
                if (h < H) el[(size_t)n * H + h] = s;
                else       er[(size_t)n * H + h - H] = s;
            }
        }
    }
}

// ---------- CSR build ----------
__global__ void count_deg(const int* __restrict__ dst, int* __restrict__ deg, int E) {
    int stride = gridDim.x * blockDim.x;
    for (int i = blockIdx.x * blockDim.x + threadIdx.x; i < E; i += stride)
        atomicAdd(&deg[dst[i]], 1);
}

// ---------- hierarchical exclusive scan (replaces single-block build_rowptr) ----------
// scan_local: each block scans 2048 elems (8/thread), writes local-exclusive rowptr
// and block total to bsum.
__global__ __launch_bounds__(256) void scan_local(const int* __restrict__ deg,
                                                  int* __restrict__ rowptr,
                                                  int* __restrict__ bsum, int N) {
    __shared__ int wsum[4];
    int t = threadIdx.x;
    int base = blockIdx.x * 2048 + t * 8;
    int v[8];
    int s = 0;
#pragma unroll
    for (int i = 0; i < 8; ++i) {
        int idx = base + i;
        v[i] = (idx < N) ? deg[idx] : 0;
        s += v[i];
    }
    int lane = t & 63, w = t >> 6;
    int incl = s;
    for (int off = 1; off < 64; off <<= 1) {
        int o = __shfl_up(incl, off);
        if (lane >= off) incl += o;
    }
    if (lane == 63) wsum[w] = incl;
    __syncthreads();
    int woff = 0;
    for (int i = 0; i < w; ++i) woff += wsum[i];
    int run = woff + incl - s;  // exclusive prefix for this thread
#pragma unroll
    for (int i = 0; i < 8; ++i) {
        int idx = base + i;
        if (idx < N) rowptr[idx] = run;
        run += v[i];
    }
    if (t == 255) bsum[blockIdx.x] = woff + incl;
}

// scan_bsum: one wave scans block totals (nb <= 64), writes exclusive offsets + total.
__global__ void scan_bsum(int* __restrict__ bsum, int* __restrict__ rowptrN, int nb) {
    int t = threadIdx.x;  // 64 threads
    int v = (t < nb) ? bsum[t] : 0;
    int incl = v;
    for (int off = 1; off < 64; off <<= 1) {
        int o = __shfl_up(incl, off);
        if (t >= off) incl += o;
    }
    if (t < nb) bsum[t] = incl - v;
    if (t == 63) *rowptrN = incl;
}

// scan_add: add block offsets.
__global__ __launch_bounds__(256) void scan_add(int* __restrict__ rowptr,
                                                const int* __restrict__ bsum, int N) {
    int off = bsum[blockIdx.x];
    if (off == 0) return;
    int base = blockIdx.x * 2048 + threadIdx.x * 8;
#pragma unroll
    for (int i = 0; i < 8; ++i) {
        int idx = base + i;
        if (idx < N) rowptr[idx] += off;
    }
}

__global__ void fill_adj(const int* __restrict__ src, const int* __restrict__ dst,
                         int* __restrict__ cursor, int* __restrict__ adj,
                         int* __restrict__ dslot, int E) {
    int stride = gridDim.x * blockDim.x;
    for (int i = blockIdx.x * blockDim.x + threadIdx.x; i < E; i += stride) {
        int d = dst[i];
        int pos = atomicAdd(&cursor[d], 1);
        adj[pos] = src[i];
        dslot[pos] = d;
    }
}

// ---------- graph segment boundaries from SORTED gid ----------
__global__ void gstart_build(const int* __restrict__ gid, int* __restrict__ gstart,
                             int N, int NG) {
    int stride = gridDim.x * blockDim.x;
    for (int n = blockIdx.x * blockDim.x + threadIdx.x; n < N; n += stride) {
        int gcur = gid[n];
        int gprev = (n == 0) ? -1 : gid[n - 1];
        for (int g = gprev + 1; g <= gcur; ++g) gstart[g] = n;
        if (n == N - 1)
            for (int g = gcur + 1; g <= NG; ++g) gstart[g] = N;
    }
}

// ---------- per-slot raw attention logits ----------
template <int H>
__global__ void edge_e(const int* __restrict__ adj, const int* __restrict__ dslot,
                       const float* __restrict__ el, const float* __restrict__ er,
                       float* __restrict__ e, int E) {
    int stride = gridDim.x * blockDim.x;
    for (int i = blockIdx.x * blockDim.x + threadIdx.x; i < E; i += stride) {
        int s = adj[i], d = dslot[i];
        const float* els = el + (size_t)s * H;
        const float* erd = er + (size_t)d * H;
#pragma unroll
        for (int h = 0; h < H; ++h)
            e[(size_t)i * H + h] = lrelu(els[h] + erd[h]);
    }
}

// ---------- per-node softmax normalize ----------
template <int H>
__global__ void node_norm(const int* __restrict__ rowptr, const float* __restrict__ e,
                          float* __restrict__ alpha, int N) {
    int stride = gridDim.x * blockDim.x;
    for (int n = blockIdx.x * blockDim.x + threadIdx.x; n < N; n += stride) {
        int rbeg = rowptr[n], rend = rowptr[n + 1];
        if (rbeg == rend) continue;
        float m[H], den[H];
#pragma unroll
        for (int h = 0; h < H; ++h) { m[h] = -INFINITY; den[h] = 0.f; }
        for (int j = rbeg; j < rend; ++j) {
#pragma unroll
            for (int h = 0; h < H; ++h) {
                float ev = e[(size_t)j * H + h];
                float newm = fmaxf(m[h], ev);
                den[h] = den[h] * __expf(m[h] - newm) + __expf(ev - newm);
                m[h] = newm;
            }
        }
        float inv[H];
#pragma unroll
        for (int h = 0; h < H; ++h) inv[h] = 1.f / fmaxf(den[h], 1e-9f);
        for (int j = rbeg; j < rend; ++j) {
#pragma unroll
            for (int h = 0; h < H; ++h)
                alpha[(size_t)j * H + h] = __expf(e[(size_t)j * H + h] - m[h]) * inv[h];
        }
    }
}

// ---------- gather RAW input rows weighted by alpha ----------
template <int H>
__global__ __launch_bounds__(256, 8) void gather_z(
        const int* __restrict__ rowptr, const int* __restrict__ adj,
        const float* __restrict__ alpha, const float* __restrict__ x,
        float* __restrict__ z, int N) {
    int lane = threadIdx.x & 63;
    int w = threadIdx.x >> 6;
    int wpb = blockDim.x >> 6;
    int wstride = gridDim.x * wpb;
    for (int n = blockIdx.x * wpb + w; n < N; n += wstride) {
        int rbeg = __builtin_amdgcn_readfirstlane(rowptr[n]);
        int rend = __builtin_amdgcn_readfirstlane(rowptr[n + 1]);
        float acc[H];
#pragma unroll
        for (int h = 0; h < H; ++h) acc[h] = 0.f;
        for (int j = rbeg; j < rend; ++j) {
            int s = __builtin_amdgcn_readfirstlane(adj[j]);
            float xv = x[(size_t)s * 64 + lane];
            const float* al = alpha + (size_t)j * H;
#pragma unroll
            for (int h = 0; h < H; ++h) acc[h] += al[h] * xv;
        }
#pragma unroll
        for (int h = 0; h < H; ++h)
            z[(size_t)n * (H * 64) + h * 64 + lane] = acc[h];
    }
}

// ---------- pack W[64][C] into per-lane bf16 MFMA B-fragments ----------
__global__ void prep_wfrag(const float* __restrict__ W, unsigned short* __restrict__ F,
                           int C) {
    int total = (C >> 4) * 1024;
    int stride = gridDim.x * blockDim.x;
    for (int idx = blockIdx.x * blockDim.x + threadIdx.x; idx < total; idx += stride) {
        int j = idx & 7;
        int lane = (idx >> 3) & 63;
        int step = (idx >> 9) & 1;
        int CT = idx >> 10;
        int k = ((lane >> 4) << 3) + j + (step << 5);
        int col = (CT << 4) + (lane & 15);
        F[idx] = f2bf(W[(size_t)k * C + col]);
    }
}

// ---------- MFMA per-head projection + relu + head-sum ----------
template <int H>
__global__ __launch_bounds__(256) void gemm_heads_mfma(
        const float* __restrict__ z, const bf16x8* __restrict__ Wf,
        const float* __restrict__ bias, float* __restrict__ out, int N) {
    const int SA = H * 64;
    int lane = threadIdx.x & 63;
    int w = threadIdx.x >> 6;
    int row0 = blockIdx.x * 64 + w * 16;
    int arow = row0 + (lane & 15);
    if (arow > N - 1) arow = N - 1;
    int kb = (lane >> 4) * 8;
    int colL = lane & 15;

    f32x4 o0 = {0,0,0,0}, o1 = {0,0,0,0}, o2 = {0,0,0,0}, o3 = {0,0,0,0};

    for (int h = 0; h < H; ++h) {
        const float* zr = z + (size_t)arow * SA + h * 64 + kb;
        float4 a0 = *reinterpret_cast<const float4*>(zr);
        float4 a1 = *reinterpret_cast<const float4*>(zr + 4);
        float4 a2 = *reinterpret_cast<const float4*>(zr + 32);
        float4 a3 = *reinterpret_cast<const float4*>(zr + 36);
        bf16x8 A0, A1;
        A0[0] = (short)f2bf(a0.x); A0[1] = (short)f2bf(a0.y);
        A0[2] = (short)f2bf(a0.z); A0[3] = (short)f2bf(a0.w);
        A0[4] = (short)f2bf(a1.x); A0[5] = (short)f2bf(a1.y);
        A0[6] = (short)f2bf(a1.z); A0[7] = (short)f2bf(a1.w);
        A1[0] = (short)f2bf(a2.x); A1[1] = (short)f2bf(a2.y);
        A1[2] = (short)f2bf(a2.z); A1[3] = (short)f2bf(a2.w);
        A1[4] = (short)f2bf(a3.x); A1[5] = (short)f2bf(a3.y);
        A1[6] = (short)f2bf(a3.z); A1[7] = (short)f2bf(a3.w);

        f32x4 acc0 = {0,0,0,0}, acc1 = {0,0,0,0}, acc2 = {0,0,0,0}, acc3 = {0,0,0,0};
#define CT_STEP(accv, ct)                                                            \
        {                                                                            \
            bf16x8 B0 = Wf[((h * 4 + (ct)) * 2 + 0) * 64 + lane];                    \
            bf16x8 B1 = Wf[((h * 4 + (ct)) * 2 + 1) * 64 + lane];                    \
            accv = __builtin_amdgcn_mfma_f32_16x16x32_bf16(A0, B0, accv, 0, 0, 0);   \
            accv = __builtin_amdgcn_mfma_f32_16x16x32_bf16(A1, B1, accv, 0, 0, 0);   \
        }
        CT_STEP(acc0, 0) CT_STEP(acc1, 1) CT_STEP(acc2, 2) CT_STEP(acc3, 3)
#undef CT_STEP

#define EPI(ov, accv, ct)                                                            \
        {                                                                            \
            float bv = bias[h * 64 + (ct) * 16 + colL];                              \
            ov[0] += fmaxf(accv[0] + bv, 0.f);                                       \
            ov[1] += fmaxf(accv[1] + bv, 0.f);                                       \
            ov[2] += fmaxf(accv[2] + bv, 0.f);                                       \
            ov[3] += fmaxf(accv[3] + bv, 0.f);                                       \
        }
        EPI(o0, acc0, 0) EPI(o1, acc1, 1) EPI(o2, acc2, 2) EPI(o3, acc3, 3)
#undef EPI
    }

    int rbase = row0 + (lane >> 4) * 4;
#define ST(ov, ct)                                                                   \
    {                                                                                \
        _Pragma("unroll")                                                            \
        for (int r = 0; r < 4; ++r) {                                                \
            int row = rbase + r;                                                     \
            if (row < N) out[(size_t)row * 64 + (ct) * 16 + colL] = ov[r];           \
        }                                                                            \
    }
    ST(o0, 0) ST(o1, 1) ST(o2, 2) ST(o3, 3)
#undef ST
}

// ---------- MFMA layer-2 GEMM: rst2 = relu(z2[N,64] @ W2[64,128] + bias) ----------
__global__ __launch_bounds__(256) void gemm_relu_mfma(
        const float* __restrict__ z, const bf16x8* __restrict__ Wf,
        const float* __restrict__ bias, float* __restrict__ out, int N) {
    int lane = threadIdx.x & 63;
    int w = threadIdx.x >> 6;
    int row0 = blockIdx.x * 64 + w * 16;
    int arow = row0 + (lane & 15);
    if (arow > N - 1) arow = N - 1;
    int kb = (lane >> 4) * 8;
    int colL = lane & 15;

    const float* zr = z + (size_t)arow * 64 + kb;
    float4 a0 = *reinterpret_cast<const float4*>(zr);
    float4 a1 = *reinterpret_cast<const float4*>(zr + 4);
    float4 a2 = *reinterpret_cast<const float4*>(zr + 32);
    float4 a3 = *reinterpret_cast<const float4*>(zr + 36);
    bf16x8 A0, A1;
    A0[0] = (short)f2bf(a0.x); A0[1] = (short)f2bf(a0.y);
    A0[2] = (short)f2bf(a0.z); A0[3] = (short)f2bf(a0.w);
    A0[4] = (short)f2bf(a1.x); A0[5] = (short)f2bf(a1.y);
    A0[6] = (short)f2bf(a1.z); A0[7] = (short)f2bf(a1.w);
    A1[0] = (short)f2bf(a2.x); A1[1] = (short)f2bf(a2.y);
    A1[2] = (short)f2bf(a2.z); A1[3] = (short)f2bf(a2.w);
    A1[4] = (short)f2bf(a3.x); A1[5] = (short)f2bf(a3.y);
    A1[6] = (short)f2bf(a3.z); A1[7] = (short)f2bf(a3.w);

    int rbase = row0 + (lane >> 4) * 4;
#define DO_CT(ct)                                                                    \
    {                                                                                \
        bf16x8 B0 = Wf[((ct) * 2 + 0) * 64 + lane];                                  \
        bf16x8 B1 = Wf[((ct) * 2 + 1) * 64 + lane];                                  \
        f32x4 acc = {0, 0, 0, 0};                                                    \
        acc = __builtin_amdgcn_mfma_f32_16x16x32_bf16(A0, B0, acc, 0, 0, 0);         \
        acc = __builtin_amdgcn_mfma_f32_16x16x32_bf16(A1, B1, acc, 0, 0, 0);         \
        float bv = bias[(ct) * 16 + colL];                                           \
        _Pragma("unroll")                                                            \
        for (int r = 0; r < 4; ++r) {                                                \
            int row = rbase + r;                                                     \
            if (row < N)                                                             \
                out[(size_t)row * 128 + (ct) * 16 + colL] = fmaxf(acc[r] + bv, 0.f); \
        }                                                                            \
    }
    DO_CT(0) DO_CT(1) DO_CT(2) DO_CT(3) DO_CT(4) DO_CT(5) DO_CT(6) DO_CT(7)
#undef DO_CT
}

// ---------- per-graph column max, no atomics ----------
__global__ __launch_bounds__(128) void graph_max(const float* __restrict__ rst2,
                                                 const int* __restrict__ gstart,
                                                 float* __restrict__ gm) {
    int g = blockIdx.x, sp = blockIdx.y;
    int t = threadIdx.x;
    int rb = gstart[g], re = gstart[g + 1];
    float m = -INFINITY;
    for (int r = rb + sp; r < re; r += 8)
        m = fmaxf(m, rst2[(size_t)r * 128 + t]);
    gm[(size_t)sp * 4096 + g * 128 + t] = m;
}

// ---------- head MLP ----------
__global__ void mlp_head(const float* __restrict__ gml, const float* __restrict__ gmr,
                         const float* __restrict__ W1, const float* __restrict__ b1,
                         const float* __restrict__ W2, const float* __restrict__ b2,
                         float* __restrict__ out) {
    __shared__ float hcat[32][256];
    __shared__ float h[32][128];
    int t = threadIdx.x;
    for (int i = t; i < 32 * 128; i += 256) {
        int r = i / 128, c = i % 128;
        float ml = -INFINITY, mr = -INFINITY;
#pragma unroll
        for (int sp = 0; sp < 8; ++sp) {
            ml = fmaxf(ml, gml[sp * 4096 + i]);
            mr = fmaxf(mr, gmr[sp * 4096 + i]);
        }
        hcat[r][c] = fmaxf(ml, 0.f);
        hcat[r][128 + c] = fmaxf(mr, 0.f);
    }
    __syncthreads();
    for (int i = t; i < 32 * 128; i += 256) {
        int r = i / 128, c = i % 128;
        float acc = b1[c];
        for (int k = 0; k < 256; ++k) acc += hcat[r][k] * W1[k * 128 + c];
        h[r][c] = acc > 0.f ? acc : 0.f;
    }
    __syncthreads();
    if (t < 32) {
        float acc = b2[0];
        for (int k = 0; k < 128; ++k) acc += h[t][k] * W2[k];
        out[t] = acc > 0.f ? acc : 0.f;
    }
}

// ---------- launch ----------
static inline unsigned nblk_elem(long long total) {
    long long b = (total + 255) / 256;
    if (b > 65535) b = 65535;
    if (b < 1) b = 1;
    return (unsigned)b;
}
static inline unsigned nblk_gather(long long nodes) {
    long long b = (nodes + 3) / 4;
    if (b > 65535) b = 65535;
    if (b < 1) b = 1;
    return (unsigned)b;
}

extern "C" void kernel_launch(void* const* d_in, const int* in_sizes, int n_in,
                              void* d_out, int out_size, void* d_ws, size_t ws_size,
                              hipStream_t stream) {
    const float* lig_x = (const float*)d_in[0];
    const int* lig_src = (const int*)d_in[1];
    const int* lig_dst = (const int*)d_in[2];
    const int* lig_gid = (const int*)d_in[3];
    const float* rec_x = (const float*)d_in[4];
    const int* rec_src = (const int*)d_in[5];
    const int* rec_dst = (const int*)d_in[6];
    const int* rec_gid = (const int*)d_in[7];
    const float* W1l = (const float*)d_in[8];
    const float* al1l = (const float*)d_in[9];
    const float* ar1l = (const float*)d_in[10];
    const float* b1l = (const float*)d_in[11];
    const float* W2l = (const float*)d_in[12];
    const float* al2l = (const float*)d_in[13];
    const float* ar2l = (const float*)d_in[14];
    const float* b2l = (const float*)d_in[15];
    const float* W1r = (const float*)d_in[16];
    const float* al1r = (const float*)d_in[17];
    const float* ar1r = (const float*)d_in[18];
    const float* b1r = (const float*)d_in[19];
    const float* W2r = (const float*)d_in[20];
    const float* al2r = (const float*)d_in[21];
    const float* ar2r = (const float*)d_in[22];
    const float* b2r = (const float*)d_in[23];
    const float* Wlin1 = (const float*)d_in[24];
    const float* blin1 = (const float*)d_in[25];
    const float* Wlin2 = (const float*)d_in[26];
    const float* blin2 = (const float*)d_in[27];

    int Nl = in_sizes[0] / 64, El = in_sizes[1];
    int Nr = in_sizes[4] / 64, Er = in_sizes[5];
    long long Nmax = Nl > Nr ? Nl : Nr;
    long long Emax = El > Er ? El : Er;

    // workspace layout
    char* ws = (char*)d_ws;
    float* z = (float*)ws;           ws += Nmax * 640 * 4;
    float* h1 = (float*)ws;          ws += Nmax * 64 * 4;
    float* elb = (float*)ws;         ws += Nmax * 10 * 4;
    float* erb = (float*)ws;         ws += Nmax * 10 * 4;
    int* deg = (int*)ws;             ws += Nmax * 4;
    int* cursor = (int*)ws;          ws += Nmax * 4;
    int* rowptr = (int*)ws;          ws += (Nmax + 1) * 4;
    int* adj = (int*)ws;             ws += Emax * 4;
    int* dslot = (int*)ws;           ws += Emax * 4;
    float* ebuf = (float*)ws;        ws += Emax * 10 * 4;
    float* alpha = (float*)ws;       ws += Emax * 10 * 4;
    float* gml = (float*)ws;         ws += 8 * 32 * 128 * 4;
    float* gmr = (float*)ws;         ws += 8 * 32 * 128 * 4;
    float* Walr = (float*)ws;        ws += 64 * 32 * 4;
    int* gstart = (int*)ws;          ws += 40 * 4;
    int* bsum = (int*)ws;            ws += 64 * 4;
    unsigned short* wf1 = (unsigned short*)ws;  ws += 40960 * 2;
    unsigned short* wf2 = (unsigned short*)ws;  ws += 8192 * 2;
    float* z2 = z;                    // [N,64]
    float* rst2 = z + Nmax * 64;      // [N,128]

    auto run_branch = [&](const float* x, const int* src, const int* dst, const int* gid,
                          const float* W1, const float* al1, const float* ar1, const float* b1,
                          const float* W2, const float* al2, const float* ar2, const float* b2,
                          float* gm, int N, int E) {
        int nb = (N + 2047) / 2048;
        // CSR + graph boundaries + weight fragments
        hipMemsetAsync(deg, 0, (size_t)N * 4, stream);
        count_deg<<<nblk_elem(E), 256, 0, stream>>>(dst, deg, E);
        scan_local<<<nb, 256, 0, stream>>>(deg, rowptr, bsum, N);
        scan_bsum<<<1, 64, 0, stream>>>(bsum, rowptr + N, nb);
        scan_add<<<nb, 256, 0, stream>>>(rowptr, bsum, N);
        hipMemcpyAsync(cursor, rowptr, (size_t)N * 4, hipMemcpyDeviceToDevice, stream);
        fill_adj<<<nblk_elem(E), 256, 0, stream>>>(src, dst, cursor, adj, dslot, E);
        gstart_build<<<nblk_elem(N), 256, 0, stream>>>(gid, gstart, N, 32);
        prep_wfrag<<<40, 256, 0, stream>>>(W1, wf1, 640);
        prep_wfrag<<<8, 256, 0, stream>>>(W2, wf2, 128);

        // ---- layer 1: H=10, aggregate x then project (MFMA) ----
        fold_attn<<<64, 64, 0, stream>>>(W1, al1, ar1, Walr, 10, 64);
        attn_from_x<<<nblk_gather(N), 256, 0, stream>>>(x, Walr, elb, erb, N, 10);
        edge_e<10><<<nblk_elem(E), 256, 0, stream>>>(adj, dslot, elb, erb, ebuf, E);
        node_norm<10><<<nblk_elem(N), 256, 0, stream>>>(rowptr, ebuf, alpha, N);
        gather_z<10><<<nblk_gather(N), 256, 0, stream>>>(rowptr, adj, alpha, x, z, N);
        gemm_heads_mfma<10><<<(N + 63) / 64, 256, 0, stream>>>(z, (const bf16x8*)wf1, b1, h1, N);

        // ---- layer 2: H=1, aggregate h1 then project (MFMA), atomic-free graph max ----
        fold_attn<<<64, 64, 0, stream>>>(W2, al2, ar2, Walr, 1, 128);
        attn_from_x<<<nblk_gather(N), 256, 0, stream>>>(h1, Walr, elb, erb, N, 1);
        edge_e<1><<<nblk_elem(E), 256, 0, stream>>>(adj, dslot, elb, erb, ebuf, E);
        node_norm<1><<<nblk_elem(N), 256, 0, stream>>>(rowptr, ebuf, alpha, N);
        gather_z<1><<<nblk_gather(N), 256, 0, stream>>>(rowptr, adj, alpha, h1, z2, N);
        gemm_relu_mfma<<<(N + 63) / 64, 256, 0, stream>>>(z2, (const bf16x8*)wf2, b2, rst2, N);
        graph_max<<<dim3(32, 8), 128, 0, stream>>>(rst2, gstart, gm);
    };

    run_branch(lig_x, lig_src, lig_dst, lig_gid, W1l, al1l, ar1l, b1l, W2l, al2l, ar2l, b2l,
               gml, Nl, El);
    run_branch(rec_x, rec_src, rec_dst, rec_gid, W1r, al1r, ar1r, b1r, W2r, al2r, ar2r, b2r,
               gmr, Nr, Er);

    mlp_head<<<1, 256, 0, stream>>>(gml, gmr, Wlin1, blin1, Wlin2, blin2, (float*)d_out);
}